// Round 7
// baseline (90.417 us; speedup 1.0000x reference)
//
#include <hip/hip_runtime.h>
#include <math.h>

// Problem constants (from reference)
#define BB    8
#define HMC   2
#define HW    41344           // 152*272
#define EMBD  128
#define KOBJ  128
#define KG    8192
#define NID0  500
#define NID1  300
#define TE    16              // entries per reid tile (one tile per active block)

// d_ws layout (words):
//   [0] pos_loss [1] neg_loss [2] num_pos [3] num_wh [4] num_off [5] mask_sum
//   [6] nll0 [7] nll1  (float)   [8] cnt0 [9] cnt1 (int)  [10] done-counter
//   [16 .. 16+KG)  idx0    [16+KG .. 16+2KG)  idx1
// (memset node zeroes words 0..15 each replay)

__device__ __forceinline__ float wave_sum(float v) {
    #pragma unroll
    for (int o = 32; o > 0; o >>= 1) v += __shfl_down(v, o, 64);
    return v;
}

// ---------------- K1: fused compact + focal + reg ----------------
__global__ __launch_bounds__(256)
void fused1_kernel(const float4* __restrict__ hp,
                   const float4* __restrict__ gt,
                   const int4*   __restrict__ cmap,
                   const float*  __restrict__ wh_pred,
                   const float*  __restrict__ reg_pred,
                   const float*  __restrict__ wh,
                   const float*  __restrict__ reg,
                   const float*  __restrict__ mask,
                   const int*    __restrict__ ind,
                   float* __restrict__ wsf, int n4, int nc4) {
    int* wsi = (int*)wsf;
    int tid = threadIdx.x;
    int gid = blockIdx.x * blockDim.x + tid;
    int gstride = gridDim.x * blockDim.x;

    __shared__ int stage0[1024], stage1[1024];   // 512 blocks -> <=648 matches/block even adversarially
    __shared__ int lcnt0, lcnt1, gbase0, gbase1;
    __shared__ float sm[3][4];

    if (tid == 0) { lcnt0 = 0; lcnt1 = 0; }
    __syncthreads();

    // compaction of cls_id_map matches (LDS staging, 2 global atomics/block)
    for (int i = gid; i < nc4; i += gstride) {
        int4 v = cmap[i];
        int b4 = i * 4;
        if (v.x == 0) stage0[atomicAdd(&lcnt0,1)] = b4+0; else if (v.x == 1) stage1[atomicAdd(&lcnt1,1)] = b4+0;
        if (v.y == 0) stage0[atomicAdd(&lcnt0,1)] = b4+1; else if (v.y == 1) stage1[atomicAdd(&lcnt1,1)] = b4+1;
        if (v.z == 0) stage0[atomicAdd(&lcnt0,1)] = b4+2; else if (v.z == 1) stage1[atomicAdd(&lcnt1,1)] = b4+2;
        if (v.w == 0) stage0[atomicAdd(&lcnt0,1)] = b4+3; else if (v.w == 1) stage1[atomicAdd(&lcnt1,1)] = b4+3;
    }
    __syncthreads();
    if (tid == 0) gbase0 = (lcnt0 > 0) ? atomicAdd(wsi + 8, lcnt0) : 0;
    if (tid == 1) gbase1 = (lcnt1 > 0) ? atomicAdd(wsi + 9, lcnt1) : 0;
    __syncthreads();
    for (int j = tid; j < lcnt0; j += 256) { int q = gbase0 + j; if (q < KG) wsi[16 + q] = stage0[j]; }
    for (int j = tid; j < lcnt1; j += 256) { int q = gbase1 + j; if (q < KG) wsi[16 + KG + q] = stage1[j]; }

    // focal loss
    {
        float pos = 0.f, neg = 0.f, cnt = 0.f;
        for (int i = gid; i < n4; i += gstride) {
            float4 x = hp[i];
            float4 g = gt[i];
            float xs[4] = {x.x, x.y, x.z, x.w};
            float gs[4] = {g.x, g.y, g.z, g.w};
            #pragma unroll
            for (int j = 0; j < 4; ++j) {
                float s = 1.f / (1.f + __expf(-xs[j]));
                s = fminf(fmaxf(s, 1e-4f), 1.f - 1e-4f);
                float gv = gs[j];
                if (gv == 1.f) {
                    float om = 1.f - s;
                    pos += __logf(s) * om * om;
                    cnt += 1.f;
                } else {
                    float nw = 1.f - gv; nw = nw * nw; nw = nw * nw;
                    neg += __logf(1.f - s) * s * s * nw;
                }
            }
        }
        float a = wave_sum(pos), b = wave_sum(neg), c = wave_sum(cnt);
        int lane = tid & 63, wid = tid >> 6;
        if (lane == 0) { sm[0][wid] = a; sm[1][wid] = b; sm[2][wid] = c; }
        __syncthreads();
        if (tid == 0) {
            float s0 = 0, s1 = 0, s2 = 0;
            #pragma unroll
            for (int w = 0; w < 4; ++w) { s0 += sm[0][w]; s1 += sm[1][w]; s2 += sm[2][w]; }
            atomicAdd(wsf + 0, s0);
            atomicAdd(wsf + 1, s1);
            atomicAdd(wsf + 2, s2);
        }
    }

    // wh / off L1 (block 0 only)
    if (blockIdx.x == 0) {
        __syncthreads();
        float nwh = 0.f, noff = 0.f, msum = 0.f;
        for (int t = tid; t < BB * KOBJ; t += 256) {
            int b = t / KOBJ;
            float m = mask[t];
            int id = ind[t];
            const float* wp = wh_pred + (size_t)b * 2 * HW;
            const float* rp = reg_pred + (size_t)b * 2 * HW;
            float p0 = wp[id], p1 = wp[HW + id];
            float q0 = rp[id], q1 = rp[HW + id];
            float t0 = wh[t * 2], t1 = wh[t * 2 + 1];
            float r0 = reg[t * 2], r1 = reg[t * 2 + 1];
            nwh  += fabsf(p0 * m - t0 * m) + fabsf(p1 * m - t1 * m);
            noff += fabsf(q0 * m - r0 * m) + fabsf(q1 * m - r1 * m);
            msum += m;
        }
        float a = wave_sum(nwh), b = wave_sum(noff), c = wave_sum(msum);
        int lane = tid & 63, wid = tid >> 6;
        if (lane == 0) { sm[0][wid] = a; sm[1][wid] = b; sm[2][wid] = c; }
        __syncthreads();
        if (tid == 0) {
            float s0 = 0, s1 = 0, s2 = 0;
            #pragma unroll
            for (int w = 0; w < 4; ++w) { s0 += sm[0][w]; s1 += sm[1][w]; s2 += sm[2][w]; }
            wsf[3] = s0; wsf[4] = s1; wsf[5] = s2;
        }
    }
}

__device__ void final_combine(const float* wsf, const float* sdet, const float* sid,
                              float* out) {
    const int* wsi = (const int*)wsf;
    float pos  = wsf[0], neg = wsf[1], npos = wsf[2];
    float swh  = wsf[3], soff = wsf[4], msum = wsf[5];
    float nll0 = wsf[6], nll1 = wsf[7];
    int c0 = wsi[8], c1 = wsi[9];
    float hm_loss = (npos > 0.f) ? -(pos + neg) / fmaxf(npos, 1.f) : -neg;
    float wh_loss  = swh  / (msum * 2.f + 1e-4f);
    float off_loss = soff / (msum * 2.f + 1e-4f);
    float reid = 0.f;
    if (c0 > 0) {
        float nv = (float)(c0 < KG ? c0 : KG);
        reid += (nll0 / fmaxf(nv, 1.f)) / fmaxf((float)c0, 1.f);
    }
    if (c1 > 0) {
        float nv = (float)(c1 < KG ? c1 : KG);
        reid += (nll1 / fmaxf(nv, 1.f)) / fmaxf((float)c1, 1.f);
    }
    float det = hm_loss + 0.1f * wh_loss + off_loss;
    float sd = sdet[0], si = sid[0];
    out[0] = 0.5f * (__expf(-sd) * det + __expf(-si) * reid + sd + si);
    out[1] = hm_loss;
    out[2] = wh_loss;
    out[3] = off_loss;
    out[4] = reid;
}

// ---------------- K2: fused gather + logits + lse + final ----------------
// grid (KG/TE, 2) x 512 threads; blockIdx.y = class; ~208 active blocks, rest exit.
// 512 threads: gather = 32 thr/entry x 4 channels; logits = ONE W-row per thread.
__global__ __launch_bounds__(512)
void reid_fused_kernel(const float* __restrict__ id_pred,
                       const int*   __restrict__ cls_tr,
                       const float* __restrict__ W0, const float* __restrict__ b0,
                       const float* __restrict__ W1, const float* __restrict__ b1,
                       const float* __restrict__ sdet, const float* __restrict__ sid,
                       float* __restrict__ wsf, float* __restrict__ out,
                       float esc0, float esc1) {
    int* wsi = (int*)wsf;
    int tid = threadIdx.x;
    int cls = blockIdx.y;

    int c0full = wsi[8], c1full = wsi[9];     // written by K1 (prior kernel, visible)
    int m0 = c0full < KG ? c0full : KG;
    int m1 = c1full < KG ? c1full : KG;
    int a0 = (m0 + TE - 1) / TE, a1 = (m1 + TE - 1) / TE;
    int nact = a0 + a1;

    if (nact == 0) {
        if (blockIdx.x == 0 && cls == 0 && tid == 0)
            final_combine(wsf, sdet, sid, out);
        return;
    }
    int m = cls ? m1 : m0;
    int base = blockIdx.x * TE;
    if (base >= m) return;
    int nval = m - base; if (nval > TE) nval = TE;

    const int nid = cls ? NID1 : NID0;
    const float* Wc = cls ? W1 : W0;
    const float* bc = cls ? b1 : b0;
    const int* idxArr = wsi + 16 + cls * KG;
    const float escale = cls ? esc1 : esc0;

    __shared__ float emb_s[TE][EMBD];
    __shared__ int   tgt_s[TE];
    __shared__ float tgtl_s[TE];
    __shared__ float red_m[TE][8];
    __shared__ float red_s[TE][8];

    // ---- gather: 32 threads per entry, 4 channels each ----
    {
        int e  = tid >> 5;          // entry 0..15
        int cg = tid & 31;          // channel group 0..31
        if (e < nval) {
            int p = idxArr[base + e];
            int b = p / HW, hw = p - b * HW;
            const float* src = id_pred + (size_t)b * EMBD * HW + hw;
            float f0 = src[(size_t)(cg * 4 + 0) * HW];
            float f1 = src[(size_t)(cg * 4 + 1) * HW];
            float f2 = src[(size_t)(cg * 4 + 2) * HW];
            float f3 = src[(size_t)(cg * 4 + 3) * HW];
            float ss = f0*f0 + f1*f1 + f2*f2 + f3*f3;
            #pragma unroll
            for (int o = 1; o < 32; o <<= 1) ss += __shfl_xor(ss, o, 64);
            float scale = escale / fmaxf(__builtin_sqrtf(ss), 1e-12f);
            *(float4*)&emb_s[e][cg * 4] = make_float4(f0*scale, f1*scale, f2*scale, f3*scale);
        } else {
            *(float4*)&emb_s[e][cg * 4] = make_float4(0.f, 0.f, 0.f, 0.f);
        }
        if (tid < TE) {
            int tg = -1;
            if (tid < nval) {
                int p = idxArr[base + tid];
                int b = p / HW, hw = p - b * HW;
                tg = cls_tr[((size_t)b * 2 + cls) * HW + hw];
            }
            tgt_s[tid] = tg;
            tgtl_s[tid] = 0.f;
        }
    }
    __syncthreads();

    // ---- logits: one W-row per thread (nid <= 512) ----
    int r = tid;
    bool rok = r < nid;
    const float4* wr = (const float4*)(Wc + (size_t)(rok ? r : 0) * EMBD);

    float acc[TE];
    #pragma unroll
    for (int e = 0; e < TE; ++e) acc[e] = 0.f;

    for (int j = 0; j < EMBD / 4; ++j) {
        float4 w = wr[j];
        #pragma unroll
        for (int e = 0; e < TE; ++e) {
            float4 em = ((const float4*)emb_s[e])[j];   // wave-broadcast LDS read
            acc[e] = fmaf(w.x, em.x, fmaf(w.y, em.y, fmaf(w.z, em.z, fmaf(w.w, em.w, acc[e]))));
        }
    }
    float bias = rok ? bc[r] : 0.f;
    #pragma unroll
    for (int e = 0; e < TE; ++e) {
        acc[e] = rok ? (acc[e] + bias) : -1e30f;
        if (rok && r == tgt_s[e]) tgtl_s[e] = acc[e];
    }

    int lane = tid & 63, wid = tid >> 6;   // 8 waves

    // pass 1: max
    float mx[TE];
    #pragma unroll
    for (int e = 0; e < TE; ++e) mx[e] = acc[e];
    #pragma unroll
    for (int o = 32; o > 0; o >>= 1) {
        #pragma unroll
        for (int e = 0; e < TE; ++e) mx[e] = fmaxf(mx[e], __shfl_xor(mx[e], o, 64));
    }
    if (lane == 0) {
        #pragma unroll
        for (int e = 0; e < TE; ++e) red_m[e][wid] = mx[e];
    }
    __syncthreads();
    float bm[TE];
    #pragma unroll
    for (int e = 0; e < TE; ++e) {
        float v0 = fmaxf(red_m[e][0], red_m[e][1]);
        float v1 = fmaxf(red_m[e][2], red_m[e][3]);
        float v2 = fmaxf(red_m[e][4], red_m[e][5]);
        float v3 = fmaxf(red_m[e][6], red_m[e][7]);
        bm[e] = fmaxf(fmaxf(v0, v1), fmaxf(v2, v3));
    }

    // pass 2: sum of exps (exp(-1e30 - bm) underflows to 0 for invalid rows)
    float se[TE];
    #pragma unroll
    for (int e = 0; e < TE; ++e) se[e] = __expf(acc[e] - bm[e]);
    #pragma unroll
    for (int o = 32; o > 0; o >>= 1) {
        #pragma unroll
        for (int e = 0; e < TE; ++e) se[e] += __shfl_xor(se[e], o, 64);
    }
    if (lane == 0) {
        #pragma unroll
        for (int e = 0; e < TE; ++e) red_s[e][wid] = se[e];
    }
    __syncthreads();

    if (tid == 0) {
        float nll = 0.f;
        #pragma unroll
        for (int e = 0; e < TE; ++e) {
            if (e < nval) {
                float S = red_s[e][0] + red_s[e][1] + red_s[e][2] + red_s[e][3]
                        + red_s[e][4] + red_s[e][5] + red_s[e][6] + red_s[e][7];
                nll += bm[e] + __logf(S) - tgtl_s[e];
            }
        }
        atomicAdd(wsf + 6 + cls, nll);
        __threadfence();
        int old = atomicAdd(wsi + 10, 1);
        if (old == nact - 1)
            final_combine(wsf, sdet, sid, out);
    }
}

extern "C" void kernel_launch(void* const* d_in, const int* in_sizes, int n_in,
                              void* d_out, int out_size, void* d_ws, size_t ws_size,
                              hipStream_t stream) {
    const float* hm_pred   = (const float*)d_in[0];
    const float* wh_pred   = (const float*)d_in[1];
    const float* reg_pred  = (const float*)d_in[2];
    const float* id_pred   = (const float*)d_in[3];
    const float* hm        = (const float*)d_in[4];
    const float* wh        = (const float*)d_in[5];
    const float* reg       = (const float*)d_in[6];
    const float* reg_mask  = (const float*)d_in[7];
    const int*   ind       = (const int*)d_in[8];
    const int*   cls_map   = (const int*)d_in[9];
    const int*   cls_tr    = (const int*)d_in[10];
    const float* W0        = (const float*)d_in[11];
    const float* b0        = (const float*)d_in[12];
    const float* W1        = (const float*)d_in[13];
    const float* b1        = (const float*)d_in[14];
    const float* s_det     = (const float*)d_in[15];
    const float* s_id      = (const float*)d_in[16];

    float* wsf = (float*)d_ws;

    // zero the 16-word accumulator header each call
    hipMemsetAsync(d_ws, 0, 64, stream);

    const int n4  = (BB * HMC * HW) / 4;   // 165376
    const int nc4 = (BB * HW) / 4;         // 82688
    const float esc0 = (float)(sqrt(2.0) * log((double)NID0 - 1.0));
    const float esc1 = (float)(sqrt(2.0) * log((double)NID1 - 1.0));

    fused1_kernel<<<512, 256, 0, stream>>>(
        (const float4*)hm_pred, (const float4*)hm, (const int4*)cls_map,
        wh_pred, reg_pred, wh, reg, reg_mask, ind, wsf, n4, nc4);

    reid_fused_kernel<<<dim3(KG / TE, 2), 512, 0, stream>>>(
        id_pred, cls_tr, W0, b0, W1, b1, s_det, s_id,
        wsf, (float*)d_out, esc0, esc1);
}

// Round 8
// 89.956 us; speedup vs baseline: 1.0051x; 1.0051x over previous
//
#include <hip/hip_runtime.h>
#include <math.h>

// Problem constants (from reference)
#define BB    8
#define HMC   2
#define HW    41344           // 152*272
#define EMBD  128
#define KOBJ  128
#define KG    8192
#define NID0  500
#define NID1  300
#define TE    16              // entries per reid tile (one tile per active block)

// d_ws layout (words):
//   [0] pos_loss [1] neg_loss [2] num_pos [3] num_wh [4] num_off [5] mask_sum
//   [6] nll0 [7] nll1  (float)   [8] cnt0 [9] cnt1 (int)  [10] done-counter
//   [16 .. 16+KG)  idx0    [16+KG .. 16+2KG)  idx1
// Header zeroed each call by init_kernel (NOT hipMemsetAsync: rocclr fill
// graph-nodes measured ~98us each regardless of size -- R3/R6/R7 profiles).

__device__ __forceinline__ float wave_sum(float v) {
    #pragma unroll
    for (int o = 32; o > 0; o >>= 1) v += __shfl_down(v, o, 64);
    return v;
}

// ---------------- K0: zero the accumulator header ----------------
__global__ void init_kernel(int* __restrict__ wsi) {
    if (threadIdx.x < 16) wsi[threadIdx.x] = 0;
}

// ---------------- K1: fused compact + focal + reg ----------------
__global__ __launch_bounds__(256)
void fused1_kernel(const float4* __restrict__ hp,
                   const float4* __restrict__ gt,
                   const int4*   __restrict__ cmap,
                   const float*  __restrict__ wh_pred,
                   const float*  __restrict__ reg_pred,
                   const float*  __restrict__ wh,
                   const float*  __restrict__ reg,
                   const float*  __restrict__ mask,
                   const int*    __restrict__ ind,
                   float* __restrict__ wsf, int n4, int nc4) {
    int* wsi = (int*)wsf;
    int tid = threadIdx.x;
    int gid = blockIdx.x * blockDim.x + tid;
    int gstride = gridDim.x * blockDim.x;

    __shared__ int stage0[1024], stage1[1024];
    __shared__ int lcnt0, lcnt1, gbase0, gbase1;
    __shared__ float sm[3][4];

    if (tid == 0) { lcnt0 = 0; lcnt1 = 0; }
    __syncthreads();

    // compaction of cls_id_map matches (LDS staging, 2 global atomics/block)
    for (int i = gid; i < nc4; i += gstride) {
        int4 v = cmap[i];
        int b4 = i * 4;
        if (v.x == 0) stage0[atomicAdd(&lcnt0,1)] = b4+0; else if (v.x == 1) stage1[atomicAdd(&lcnt1,1)] = b4+0;
        if (v.y == 0) stage0[atomicAdd(&lcnt0,1)] = b4+1; else if (v.y == 1) stage1[atomicAdd(&lcnt1,1)] = b4+1;
        if (v.z == 0) stage0[atomicAdd(&lcnt0,1)] = b4+2; else if (v.z == 1) stage1[atomicAdd(&lcnt1,1)] = b4+2;
        if (v.w == 0) stage0[atomicAdd(&lcnt0,1)] = b4+3; else if (v.w == 1) stage1[atomicAdd(&lcnt1,1)] = b4+3;
    }
    __syncthreads();
    if (tid == 0) gbase0 = (lcnt0 > 0) ? atomicAdd(wsi + 8, lcnt0) : 0;
    if (tid == 1) gbase1 = (lcnt1 > 0) ? atomicAdd(wsi + 9, lcnt1) : 0;
    __syncthreads();
    for (int j = tid; j < lcnt0; j += 256) { int q = gbase0 + j; if (q < KG) wsi[16 + q] = stage0[j]; }
    for (int j = tid; j < lcnt1; j += 256) { int q = gbase1 + j; if (q < KG) wsi[16 + KG + q] = stage1[j]; }

    // focal loss
    {
        float pos = 0.f, neg = 0.f, cnt = 0.f;
        for (int i = gid; i < n4; i += gstride) {
            float4 x = hp[i];
            float4 g = gt[i];
            float xs[4] = {x.x, x.y, x.z, x.w};
            float gs[4] = {g.x, g.y, g.z, g.w};
            #pragma unroll
            for (int j = 0; j < 4; ++j) {
                float s = 1.f / (1.f + __expf(-xs[j]));
                s = fminf(fmaxf(s, 1e-4f), 1.f - 1e-4f);
                float gv = gs[j];
                if (gv == 1.f) {
                    float om = 1.f - s;
                    pos += __logf(s) * om * om;
                    cnt += 1.f;
                } else {
                    float nw = 1.f - gv; nw = nw * nw; nw = nw * nw;
                    neg += __logf(1.f - s) * s * s * nw;
                }
            }
        }
        float a = wave_sum(pos), b = wave_sum(neg), c = wave_sum(cnt);
        int lane = tid & 63, wid = tid >> 6;
        if (lane == 0) { sm[0][wid] = a; sm[1][wid] = b; sm[2][wid] = c; }
        __syncthreads();
        if (tid == 0) {
            float s0 = 0, s1 = 0, s2 = 0;
            #pragma unroll
            for (int w = 0; w < 4; ++w) { s0 += sm[0][w]; s1 += sm[1][w]; s2 += sm[2][w]; }
            atomicAdd(wsf + 0, s0);
            atomicAdd(wsf + 1, s1);
            atomicAdd(wsf + 2, s2);
        }
    }

    // wh / off L1 (block 0 only)
    if (blockIdx.x == 0) {
        __syncthreads();
        float nwh = 0.f, noff = 0.f, msum = 0.f;
        for (int t = tid; t < BB * KOBJ; t += 256) {
            int b = t / KOBJ;
            float m = mask[t];
            int id = ind[t];
            const float* wp = wh_pred + (size_t)b * 2 * HW;
            const float* rp = reg_pred + (size_t)b * 2 * HW;
            float p0 = wp[id], p1 = wp[HW + id];
            float q0 = rp[id], q1 = rp[HW + id];
            float t0 = wh[t * 2], t1 = wh[t * 2 + 1];
            float r0 = reg[t * 2], r1 = reg[t * 2 + 1];
            nwh  += fabsf(p0 * m - t0 * m) + fabsf(p1 * m - t1 * m);
            noff += fabsf(q0 * m - r0 * m) + fabsf(q1 * m - r1 * m);
            msum += m;
        }
        float a = wave_sum(nwh), b = wave_sum(noff), c = wave_sum(msum);
        int lane = tid & 63, wid = tid >> 6;
        if (lane == 0) { sm[0][wid] = a; sm[1][wid] = b; sm[2][wid] = c; }
        __syncthreads();
        if (tid == 0) {
            float s0 = 0, s1 = 0, s2 = 0;
            #pragma unroll
            for (int w = 0; w < 4; ++w) { s0 += sm[0][w]; s1 += sm[1][w]; s2 += sm[2][w]; }
            wsf[3] = s0; wsf[4] = s1; wsf[5] = s2;
        }
    }
}

__device__ void final_combine(const float* wsf, const float* sdet, const float* sid,
                              float* out) {
    const int* wsi = (const int*)wsf;
    float pos  = wsf[0], neg = wsf[1], npos = wsf[2];
    float swh  = wsf[3], soff = wsf[4], msum = wsf[5];
    float nll0 = wsf[6], nll1 = wsf[7];
    int c0 = wsi[8], c1 = wsi[9];
    float hm_loss = (npos > 0.f) ? -(pos + neg) / fmaxf(npos, 1.f) : -neg;
    float wh_loss  = swh  / (msum * 2.f + 1e-4f);
    float off_loss = soff / (msum * 2.f + 1e-4f);
    float reid = 0.f;
    if (c0 > 0) {
        float nv = (float)(c0 < KG ? c0 : KG);
        reid += (nll0 / fmaxf(nv, 1.f)) / fmaxf((float)c0, 1.f);
    }
    if (c1 > 0) {
        float nv = (float)(c1 < KG ? c1 : KG);
        reid += (nll1 / fmaxf(nv, 1.f)) / fmaxf((float)c1, 1.f);
    }
    float det = hm_loss + 0.1f * wh_loss + off_loss;
    float sd = sdet[0], si = sid[0];
    out[0] = 0.5f * (__expf(-sd) * det + __expf(-si) * reid + sd + si);
    out[1] = hm_loss;
    out[2] = wh_loss;
    out[3] = off_loss;
    out[4] = reid;
}

// ---------------- K2: fused gather + logits + lse + final ----------------
// grid (KG/TE, 2) x 512 threads; blockIdx.y = class; ~208 active blocks, rest exit.
__global__ __launch_bounds__(512)
void reid_fused_kernel(const float* __restrict__ id_pred,
                       const int*   __restrict__ cls_tr,
                       const float* __restrict__ W0, const float* __restrict__ b0,
                       const float* __restrict__ W1, const float* __restrict__ b1,
                       const float* __restrict__ sdet, const float* __restrict__ sid,
                       float* __restrict__ wsf, float* __restrict__ out,
                       float esc0, float esc1) {
    int* wsi = (int*)wsf;
    int tid = threadIdx.x;
    int cls = blockIdx.y;

    int c0full = wsi[8], c1full = wsi[9];     // written by K1 (prior kernel, visible)
    int m0 = c0full < KG ? c0full : KG;
    int m1 = c1full < KG ? c1full : KG;
    int a0 = (m0 + TE - 1) / TE, a1 = (m1 + TE - 1) / TE;
    int nact = a0 + a1;

    if (nact == 0) {
        if (blockIdx.x == 0 && cls == 0 && tid == 0)
            final_combine(wsf, sdet, sid, out);
        return;
    }
    int m = cls ? m1 : m0;
    int base = blockIdx.x * TE;
    if (base >= m) return;
    int nval = m - base; if (nval > TE) nval = TE;

    const int nid = cls ? NID1 : NID0;
    const float* Wc = cls ? W1 : W0;
    const float* bc = cls ? b1 : b0;
    const int* idxArr = wsi + 16 + cls * KG;
    const float escale = cls ? esc1 : esc0;

    __shared__ float emb_s[TE][EMBD];
    __shared__ int   tgt_s[TE];
    __shared__ float tgtl_s[TE];
    __shared__ float red_m[TE][8];
    __shared__ float red_s[TE][8];

    // ---- gather: 32 threads per entry, 4 channels each ----
    {
        int e  = tid >> 5;          // entry 0..15
        int cg = tid & 31;          // channel group 0..31
        if (e < nval) {
            int p = idxArr[base + e];
            int b = p / HW, hw = p - b * HW;
            const float* src = id_pred + (size_t)b * EMBD * HW + hw;
            float f0 = src[(size_t)(cg * 4 + 0) * HW];
            float f1 = src[(size_t)(cg * 4 + 1) * HW];
            float f2 = src[(size_t)(cg * 4 + 2) * HW];
            float f3 = src[(size_t)(cg * 4 + 3) * HW];
            float ss = f0*f0 + f1*f1 + f2*f2 + f3*f3;
            #pragma unroll
            for (int o = 1; o < 32; o <<= 1) ss += __shfl_xor(ss, o, 64);
            float scale = escale / fmaxf(__builtin_sqrtf(ss), 1e-12f);
            *(float4*)&emb_s[e][cg * 4] = make_float4(f0*scale, f1*scale, f2*scale, f3*scale);
        } else {
            *(float4*)&emb_s[e][cg * 4] = make_float4(0.f, 0.f, 0.f, 0.f);
        }
        if (tid < TE) {
            int tg = -1;
            if (tid < nval) {
                int p = idxArr[base + tid];
                int b = p / HW, hw = p - b * HW;
                tg = cls_tr[((size_t)b * 2 + cls) * HW + hw];
            }
            tgt_s[tid] = tg;
            tgtl_s[tid] = 0.f;
        }
    }
    __syncthreads();

    // ---- logits: one W-row per thread (nid <= 512) ----
    int r = tid;
    bool rok = r < nid;
    const float4* wr = (const float4*)(Wc + (size_t)(rok ? r : 0) * EMBD);

    float acc[TE];
    #pragma unroll
    for (int e = 0; e < TE; ++e) acc[e] = 0.f;

    for (int j = 0; j < EMBD / 4; ++j) {
        float4 w = wr[j];
        #pragma unroll
        for (int e = 0; e < TE; ++e) {
            float4 em = ((const float4*)emb_s[e])[j];   // wave-broadcast LDS read
            acc[e] = fmaf(w.x, em.x, fmaf(w.y, em.y, fmaf(w.z, em.z, fmaf(w.w, em.w, acc[e]))));
        }
    }
    float bias = rok ? bc[r] : 0.f;
    #pragma unroll
    for (int e = 0; e < TE; ++e) {
        acc[e] = rok ? (acc[e] + bias) : -1e30f;
        if (rok && r == tgt_s[e]) tgtl_s[e] = acc[e];
    }

    int lane = tid & 63, wid = tid >> 6;   // 8 waves

    // pass 1: max
    float mx[TE];
    #pragma unroll
    for (int e = 0; e < TE; ++e) mx[e] = acc[e];
    #pragma unroll
    for (int o = 32; o > 0; o >>= 1) {
        #pragma unroll
        for (int e = 0; e < TE; ++e) mx[e] = fmaxf(mx[e], __shfl_xor(mx[e], o, 64));
    }
    if (lane == 0) {
        #pragma unroll
        for (int e = 0; e < TE; ++e) red_m[e][wid] = mx[e];
    }
    __syncthreads();
    float bm[TE];
    #pragma unroll
    for (int e = 0; e < TE; ++e) {
        float v0 = fmaxf(red_m[e][0], red_m[e][1]);
        float v1 = fmaxf(red_m[e][2], red_m[e][3]);
        float v2 = fmaxf(red_m[e][4], red_m[e][5]);
        float v3 = fmaxf(red_m[e][6], red_m[e][7]);
        bm[e] = fmaxf(fmaxf(v0, v1), fmaxf(v2, v3));
    }

    // pass 2: sum of exps (exp(-1e30 - bm) underflows to 0 for invalid rows)
    float se[TE];
    #pragma unroll
    for (int e = 0; e < TE; ++e) se[e] = __expf(acc[e] - bm[e]);
    #pragma unroll
    for (int o = 32; o > 0; o >>= 1) {
        #pragma unroll
        for (int e = 0; e < TE; ++e) se[e] += __shfl_xor(se[e], o, 64);
    }
    if (lane == 0) {
        #pragma unroll
        for (int e = 0; e < TE; ++e) red_s[e][wid] = se[e];
    }
    __syncthreads();

    if (tid == 0) {
        float nll = 0.f;
        #pragma unroll
        for (int e = 0; e < TE; ++e) {
            if (e < nval) {
                float S = red_s[e][0] + red_s[e][1] + red_s[e][2] + red_s[e][3]
                        + red_s[e][4] + red_s[e][5] + red_s[e][6] + red_s[e][7];
                nll += bm[e] + __logf(S) - tgtl_s[e];
            }
        }
        atomicAdd(wsf + 6 + cls, nll);
        __threadfence();
        int old = atomicAdd(wsi + 10, 1);
        if (old == nact - 1)
            final_combine(wsf, sdet, sid, out);
    }
}

extern "C" void kernel_launch(void* const* d_in, const int* in_sizes, int n_in,
                              void* d_out, int out_size, void* d_ws, size_t ws_size,
                              hipStream_t stream) {
    const float* hm_pred   = (const float*)d_in[0];
    const float* wh_pred   = (const float*)d_in[1];
    const float* reg_pred  = (const float*)d_in[2];
    const float* id_pred   = (const float*)d_in[3];
    const float* hm        = (const float*)d_in[4];
    const float* wh        = (const float*)d_in[5];
    const float* reg       = (const float*)d_in[6];
    const float* reg_mask  = (const float*)d_in[7];
    const int*   ind       = (const int*)d_in[8];
    const int*   cls_map   = (const int*)d_in[9];
    const int*   cls_tr    = (const int*)d_in[10];
    const float* W0        = (const float*)d_in[11];
    const float* b0        = (const float*)d_in[12];
    const float* W1        = (const float*)d_in[13];
    const float* b1        = (const float*)d_in[14];
    const float* s_det     = (const float*)d_in[15];
    const float* s_id      = (const float*)d_in[16];

    float* wsf = (float*)d_ws;

    const int n4  = (BB * HMC * HW) / 4;   // 165376
    const int nc4 = (BB * HW) / 4;         // 82688
    const float esc0 = (float)(sqrt(2.0) * log((double)NID0 - 1.0));
    const float esc1 = (float)(sqrt(2.0) * log((double)NID1 - 1.0));

    // K0: zero the 16-word header (replaces hipMemsetAsync: rocclr fill node ~98us)
    init_kernel<<<1, 64, 0, stream>>>((int*)d_ws);

    fused1_kernel<<<512, 256, 0, stream>>>(
        (const float4*)hm_pred, (const float4*)hm, (const int4*)cls_map,
        wh_pred, reg_pred, wh, reg, reg_mask, ind, wsf, n4, nc4);

    reid_fused_kernel<<<dim3(KG / TE, 2), 512, 0, stream>>>(
        id_pred, cls_tr, W0, b0, W1, b1, s_det, s_id,
        wsf, (float*)d_out, esc0, esc1);
}